// Round 1
// baseline (215.789 us; speedup 1.0000x reference)
//
#include <hip/hip_runtime.h>

// Adaptive downsampler: B=8, C=3, 1024x1024 -> 512x512, K2=9 taps,
// bilinear gather from reflect-padded (pad=1) image, weighted by kernels.
constexpr int B_  = 8;
constexpr int C_  = 3;
constexpr int H_  = 1024;
constexpr int W_  = 1024;
constexpr int HO_ = 512;
constexpr int WO_ = 512;
constexpr int K2_ = 9;
constexpr int KS_ = 3;
constexpr int HP_ = H_ + 2;   // padded height (pad=1)
constexpr int WP_ = W_ + 2;   // padded width

__global__ __launch_bounds__(256) void ds_kernel(
    const float* __restrict__ img,
    const float* __restrict__ kern,
    const float* __restrict__ offh,
    const float* __restrict__ offv,
    const float* __restrict__ unit_p,
    float* __restrict__ out)
{
    const int HWo = HO_ * WO_;                       // 262144
    int idx = blockIdx.x * 256 + threadIdx.x;
    if (idx >= B_ * HWo) return;

    const int ox = idx & (WO_ - 1);
    const int oy = (idx >> 9) & (HO_ - 1);
    const int b  = idx >> 18;

    const float unit = unit_p[0];
    const float* imgb = img + (size_t)b * (C_ * H_ * W_);
    const size_t kbase = (size_t)b * (K2_ * HWo) + (size_t)oy * WO_ + ox;

    // (ox+0.5)/WO*W - 0.5 == 2*ox + 0.5  (exact in fp32; W/WO = 2)
    const float cx = 2.0f * (float)ox + 0.5f;
    const float cy = 2.0f * (float)oy + 0.5f;

    float acc[C_];
#pragma unroll
    for (int c = 0; c < C_; ++c) acc[c] = 0.0f;

#pragma unroll
    for (int k = 0; k < K2_; ++k) {
        const float wk = kern[kbase + (size_t)k * HWo];
        const float oh = offh[kbase + (size_t)k * HWo];
        const float ov = offv[kbase + (size_t)k * HWo];

        const float px = cx + (float)(k % KS_) + oh * unit;
        const float py = cy + (float)(k / KS_) + ov * unit;

        const float fx = floorf(px);
        const float fy = floorf(py);
        const float a  = px - fx;   // alpha in [0,1)
        const float bt = py - fy;   // beta

        // clip in PADDED coordinates [0, WP-1] / [0, HP-1]
        int xL = (int)fx; xL = xL < 0 ? 0 : (xL > WP_ - 1 ? WP_ - 1 : xL);
        int xR = xL + 1;  xR = xR > WP_ - 1 ? WP_ - 1 : xR;
        int yT = (int)fy; yT = yT < 0 ? 0 : (yT > HP_ - 1 ? HP_ - 1 : yT);
        int yB = yT + 1;  yB = yB > HP_ - 1 ? HP_ - 1 : yB;

        // padded -> original index with reflect (pad=1):
        // j = i-1; j==-1 -> 1; j==H -> H-2
        int xl = xL - 1; xl = (xl < 0) ? -xl : (xl >= W_ ? 2 * W_ - 2 - xl : xl);
        int xr = xR - 1; xr = (xr < 0) ? -xr : (xr >= W_ ? 2 * W_ - 2 - xr : xr);
        int yt = yT - 1; yt = (yt < 0) ? -yt : (yt >= H_ ? 2 * H_ - 2 - yt : yt);
        int yb = yB - 1; yb = (yb < 0) ? -yb : (yb >= H_ ? 2 * H_ - 2 - yb : yb);

        const float wtl = (1.0f - a) * (1.0f - bt) * wk;
        const float wtr = a * (1.0f - bt) * wk;
        const float wbl = (1.0f - a) * bt * wk;
        const float wbr = a * bt * wk;

        const int r0 = yt * W_;
        const int r1 = yb * W_;
#pragma unroll
        for (int c = 0; c < C_; ++c) {
            const float* ch = imgb + (size_t)c * (H_ * W_);
            const float tl = ch[r0 + xl];
            const float tr = ch[r0 + xr];
            const float bl = ch[r1 + xl];
            const float br = ch[r1 + xr];
            acc[c] += wtl * tl + wtr * tr + wbl * bl + wbr * br;
        }
    }

    const size_t obase = (size_t)b * (C_ * HWo) + (size_t)oy * WO_ + ox;
#pragma unroll
    for (int c = 0; c < C_; ++c) out[obase + (size_t)c * HWo] = acc[c];
}

extern "C" void kernel_launch(void* const* d_in, const int* in_sizes, int n_in,
                              void* d_out, int out_size, void* d_ws, size_t ws_size,
                              hipStream_t stream) {
    const float* img  = (const float*)d_in[0];
    const float* kern = (const float*)d_in[1];
    const float* offh = (const float*)d_in[2];
    const float* offv = (const float*)d_in[3];
    const float* unit = (const float*)d_in[4];
    float* out = (float*)d_out;

    const int total = B_ * HO_ * WO_;          // 2,097,152 threads
    const int block = 256;
    const int grid  = (total + block - 1) / block;   // 8192 blocks
    ds_kernel<<<grid, block, 0, stream>>>(img, kern, offh, offv, unit, out);
}